// Round 4
// baseline (91.408 us; speedup 1.0000x reference)
//
#include <hip/hip_runtime.h>

// CapsuleConv2d fused, MI355X gfx950. ALL I/O FP32.
// B=2, C_in=128 (G=8 x M=16), 32x32, 3x3 pad 1, O=16, L=16 -> C_out=256.
// k-means (dot) routing 3 iters + squash.
//
// v11 (from v10 counters: 40.7us, MfmaUtil 3.2%, VALUBusy 57%, Occ 32%,
// HBM 2% -> VALU+latency bound, W-stage/pack duplicated 4096x/512x):
//  - grid 1024 (= 4 blocks/CU, ALL resident, one residency round).
//    Block = (tt, bb, h, w-half); loops over 4 pixel-quads sequentially.
//  - B-frags: gathered DIRECTLY from global W (L2-hot 18KB/tt slice) and
//    packed ONCE per block (was: LDS stage + pack per 4096 blocks). Kills
//    the stage loop, one barrier, and 3/4 of pack VALU.
//  - Per quad: batch 8x3 A-loads first (1 latency exposure, not 3), then
//    pack+MFMA+CWR -> bar -> LROW -> bar -> register-only routing + store.
//  - Phase-2 routing numerics identical to v9/v10 (absmax must stay 4.88e-4).

typedef float v2f __attribute__((ext_vector_type(2)));
typedef int   i4  __attribute__((ext_vector_type(4)));
typedef short bh8 __attribute__((ext_vector_type(8)));
typedef float f16v __attribute__((ext_vector_type(16)));

#define STR 34                         // u LDS row stride (floats)

#define DPP_ADD(a, ctrl)                                                     \
  a += __int_as_float(__builtin_amdgcn_update_dpp(                           \
          0, __float_as_int(a), ctrl, 0xF, 0xF, true))

__device__ __forceinline__ float dpp_add16(float x) {
    float s = x;
    DPP_ADD(s, 0x128); DPP_ADD(s, 0x124); DPP_ADD(s, 0x122); DPP_ADD(s, 0x121);
    return s;
}

__device__ __forceinline__ float swz16_add(float x) {
    // x + value from lane^16 within each 32-lane group
    int y = __builtin_amdgcn_ds_swizzle(__float_as_int(x), 0x401F);
    return x + __int_as_float(y);
}

__device__ __forceinline__ float frcp(float x) {
    return __builtin_amdgcn_rcpf(x);
}

__device__ __forceinline__ v2f pkfma(v2f a, v2f b, v2f c) {
    return __builtin_elementwise_fma(a, b, c);
}

// ---- B-fragment gather from GLOBAL W + trunc-bf16 hi/lo pack ----
// lane L: t = tt*32 + (L&31), k = (L>>5)*8 + j, flat = t*144 + k*9 + ij
// Wg = W + tt*4608 + (L&31)*144 + (L>>5)*72  ->  addr = Wg + ij + 9*j
#define BFRAGG(BH, BL, IJ) {                                                 \
    const float* wp_ = Wg + (IJ);                                            \
    float q0 = wp_[0],  q1 = wp_[9],  q2 = wp_[18], q3 = wp_[27];            \
    float q4 = wp_[36], q5 = wp_[45], q6 = wp_[54], q7 = wp_[63];            \
    unsigned d0 = __float_as_uint(q0), d1 = __float_as_uint(q1);             \
    unsigned d2 = __float_as_uint(q2), d3 = __float_as_uint(q3);             \
    unsigned d4 = __float_as_uint(q4), d5 = __float_as_uint(q5);             \
    unsigned d6 = __float_as_uint(q6), d7 = __float_as_uint(q7);             \
    BH.x = (int)((d0 >> 16) | (d1 & 0xFFFF0000u));                           \
    BH.y = (int)((d2 >> 16) | (d3 & 0xFFFF0000u));                           \
    BH.z = (int)((d4 >> 16) | (d5 & 0xFFFF0000u));                           \
    BH.w = (int)((d6 >> 16) | (d7 & 0xFFFF0000u));                           \
    unsigned e0 = __float_as_uint(q0 - __uint_as_float(d0 & 0xFFFF0000u));   \
    unsigned e1 = __float_as_uint(q1 - __uint_as_float(d1 & 0xFFFF0000u));   \
    unsigned e2 = __float_as_uint(q2 - __uint_as_float(d2 & 0xFFFF0000u));   \
    unsigned e3 = __float_as_uint(q3 - __uint_as_float(d3 & 0xFFFF0000u));   \
    unsigned e4 = __float_as_uint(q4 - __uint_as_float(d4 & 0xFFFF0000u));   \
    unsigned e5 = __float_as_uint(q5 - __uint_as_float(d5 & 0xFFFF0000u));   \
    unsigned e6 = __float_as_uint(q6 - __uint_as_float(d6 & 0xFFFF0000u));   \
    unsigned e7 = __float_as_uint(q7 - __uint_as_float(d7 & 0xFFFF0000u));   \
    BL.x = (int)((e0 >> 16) | (e1 & 0xFFFF0000u));                           \
    BL.y = (int)((e2 >> 16) | (e3 & 0xFFFF0000u));                           \
    BL.z = (int)((e4 >> 16) | (e5 & 0xFFFF0000u));                           \
    BL.w = (int)((e6 >> 16) | (e7 & 0xFFFF0000u)); }

// ---- phase-1: A-load batch, then pack+MFMA+CWR ----
#define ALOAD(A, M, IJ) {                                                    \
    const int di = (IJ) / 3, dj = (IJ) % 3;                                  \
    const int hh = h + di - 1;                                               \
    const bool hok = (unsigned)hh < 32u;                                     \
    const int hhc = hok ? hh : 0;                                            \
    const int ww = w0 + pl + dj - 1;                                         \
    const bool ok = hok && ((unsigned)ww < 32u);                             \
    const int wwc = ok ? ww : 0;                                             \
    const float* ap = xq + hhc * 32 + wwc;                                   \
    M = ok ? 1.0f : 0.0f;                                                    \
    A[0] = ap[0];    A[1] = ap[1024]; A[2] = ap[2048]; A[3] = ap[3072];      \
    A[4] = ap[4096]; A[5] = ap[5120]; A[6] = ap[6144]; A[7] = ap[7168]; }

// C row r = (reg&3)+8*(reg>>2)+4*half: p=reg>>2, g=(reg&3)+4*half
#define CWR(REG, IJ)                                                         \
    uLds[wroff + STR * ((((REG) >> 2) * 72) + (((REG) & 3) * 9) + (IJ))] =   \
        acc[(REG)];

#define PACKMFMA(A, M, IJ, BH, BL) {                                         \
    float f0 = A[0]*M, f1 = A[1]*M, f2 = A[2]*M, f3 = A[3]*M;                \
    float f4 = A[4]*M, f5 = A[5]*M, f6 = A[6]*M, f7 = A[7]*M;                \
    unsigned b0 = __float_as_uint(f0), b1 = __float_as_uint(f1);             \
    unsigned b2 = __float_as_uint(f2), b3 = __float_as_uint(f3);             \
    unsigned b4 = __float_as_uint(f4), b5 = __float_as_uint(f5);             \
    unsigned b6 = __float_as_uint(f6), b7 = __float_as_uint(f7);             \
    i4 hp, lp;                                                               \
    hp.x = (int)((b0 >> 16) | (b1 & 0xFFFF0000u));                           \
    hp.y = (int)((b2 >> 16) | (b3 & 0xFFFF0000u));                           \
    hp.z = (int)((b4 >> 16) | (b5 & 0xFFFF0000u));                           \
    hp.w = (int)((b6 >> 16) | (b7 & 0xFFFF0000u));                           \
    unsigned l0 = __float_as_uint(f0 - __uint_as_float(b0 & 0xFFFF0000u));   \
    unsigned l1 = __float_as_uint(f1 - __uint_as_float(b1 & 0xFFFF0000u));   \
    unsigned l2 = __float_as_uint(f2 - __uint_as_float(b2 & 0xFFFF0000u));   \
    unsigned l3 = __float_as_uint(f3 - __uint_as_float(b3 & 0xFFFF0000u));   \
    unsigned l4 = __float_as_uint(f4 - __uint_as_float(b4 & 0xFFFF0000u));   \
    unsigned l5 = __float_as_uint(f5 - __uint_as_float(b5 & 0xFFFF0000u));   \
    unsigned l6 = __float_as_uint(f6 - __uint_as_float(b6 & 0xFFFF0000u));   \
    unsigned l7 = __float_as_uint(f7 - __uint_as_float(b7 & 0xFFFF0000u));   \
    lp.x = (int)((l0 >> 16) | (l1 & 0xFFFF0000u));                           \
    lp.y = (int)((l2 >> 16) | (l3 & 0xFFFF0000u));                           \
    lp.z = (int)((l4 >> 16) | (l5 & 0xFFFF0000u));                           \
    lp.w = (int)((l6 >> 16) | (l7 & 0xFFFF0000u));                           \
    bh8 aHi = __builtin_bit_cast(bh8, hp);                                   \
    bh8 aLo = __builtin_bit_cast(bh8, lp);                                   \
    bh8 bHi = __builtin_bit_cast(bh8, BH);                                   \
    bh8 bLo = __builtin_bit_cast(bh8, BL);                                   \
    f16v acc = {0.f,0.f,0.f,0.f,0.f,0.f,0.f,0.f,                             \
                0.f,0.f,0.f,0.f,0.f,0.f,0.f,0.f};                            \
    acc = __builtin_amdgcn_mfma_f32_32x32x16_bf16(aHi, bLo, acc, 0, 0, 0);   \
    acc = __builtin_amdgcn_mfma_f32_32x32x16_bf16(aLo, bHi, acc, 0, 0, 0);   \
    acc = __builtin_amdgcn_mfma_f32_32x32x16_bf16(aHi, bHi, acc, 0, 0, 0);   \
    CWR(0, IJ)  CWR(1, IJ)  CWR(2, IJ)  CWR(3, IJ)                           \
    CWR(4, IJ)  CWR(5, IJ)  CWR(6, IJ)  CWR(7, IJ)                           \
    CWR(8, IJ)  CWR(9, IJ)  CWR(10, IJ) CWR(11, IJ)                          \
    CWR(12, IJ) CWR(13, IJ) CWR(14, IJ) CWR(15, IJ) }

// ---- phase-2 macros (v8 lineage, 5 rows x 8 l per thread) ----
#define LROW(K)                                                              \
  { const v2f* r2_ = (const v2f*)(rb + (K) * 16 * STR);                      \
    U##K##0 = r2_[0]; U##K##1 = r2_[1]; U##K##2 = r2_[2]; U##K##3 = r2_[3]; }

#define DOTR(K)                                                              \
  ({ v2f d_ = U##K##0 * V0;                                                  \
     d_ = pkfma(U##K##1, V1, d_); d_ = pkfma(U##K##2, V2, d_);               \
     d_ = pkfma(U##K##3, V3, d_); swz16_add(d_.x + d_.y); })

#define MEANJ(J)                                                             \
  { v2f s_ = (U0##J + U1##J) + (U2##J + U3##J) + U4##J;                      \
    V##J.x = dpp_add16(s_.x) * (1.0f / 72.0f);                               \
    V##J.y = dpp_add16(s_.y) * (1.0f / 72.0f); }

#define UPDJ(J)                                                              \
  { v2f pv_ = e0v * U0##J;                                                   \
    pv_ = pkfma(e1v, U1##J, pv_); pv_ = pkfma(e2v, U2##J, pv_);              \
    pv_ = pkfma(e3v, U3##J, pv_); pv_ = pkfma(e4v, U4##J, pv_);              \
    V##J.x = dpp_add16(pv_.x) * rs;                                          \
    V##J.y = dpp_add16(pv_.y) * rs; }

// ---- main kernel v11: 1024 blocks, 4 quads/block, B-frags once ----
__global__ __launch_bounds__(256, 4)
void capsule_v11(const float* __restrict__ x, const float* __restrict__ W,
                 float* __restrict__ out) {
    __shared__ float uLds[4 * 72 * STR];     // 38.25 KB -> 4 blocks/CU
    const int blk  = blockIdx.x;             // 1024 = tt(8) x bb(2) x h(32) x wh(2)
    const int tt   = blk & 7;
    const int rest = blk >> 3;
    const int bb   = rest >> 6;
    const int h    = (rest >> 1) & 31;
    const int wh   = rest & 1;
    const int tid  = threadIdx.x;

    const int lane = tid & 63;
    const int wv   = tid >> 6;
    const int pl   = (lane & 31) >> 3;   // pixel within quad (A row>>3)
    const int gl   = lane & 7;           // group (A row&7)
    const int half = lane >> 5;          // k-half
    const int tl   = lane & 31;          // C col
    const int wroff = tl + STR * 9 * 4 * half;
    const float* xq = x + bb * 131072 + (gl * 16 + half * 8) * 1024;
    const float* Wg = W + tt * 4608 + (lane & 31) * 144 + (lane >> 5) * 72;

    // ---- B fragments: gathered from global W, packed ONCE per block ----
    i4 B0h = {0,0,0,0}, B0l = {0,0,0,0};
    i4 B1h = {0,0,0,0}, B1l = {0,0,0,0};
    i4 B2h = {0,0,0,0}, B2l = {0,0,0,0};
    if (wv == 0)      { BFRAGG(B0h,B0l,0) BFRAGG(B1h,B1l,4) BFRAGG(B2h,B2l,8) }
    else if (wv == 1) { BFRAGG(B0h,B0l,1) BFRAGG(B1h,B1l,5) }
    else if (wv == 2) { BFRAGG(B0h,B0l,2) BFRAGG(B1h,B1l,6) }
    else              { BFRAGG(B0h,B0l,3) BFRAGG(B1h,B1l,7) }

    // ---- phase-2 indices (quad-invariant) ----
    const int p  = tid >> 6;
    const int i6 = tid & 63;
    const int o2 = i6 >> 5;
    const int jh = (i6 >> 4) & 1;
    const int sc = i6 & 15;
    const bool has5 = (sc < 8);
    const float* rb = uLds + (p * 72 + sc) * STR + o2 * 16 + jh * 8;

    #pragma unroll 1
    for (int qi = 0; qi < 4; ++qi) {
        const int w0 = wh * 16 + qi * 4;

        // ---- phase 1: batched A-loads, then pack+MFMA -> u LDS ----
        {
            float a0[8], a1[8], a2[8];
            float m0, m1, m2;
            if (wv == 0) {
                ALOAD(a0, m0, 0) ALOAD(a1, m1, 4) ALOAD(a2, m2, 8)
                PACKMFMA(a0, m0, 0, B0h, B0l)
                PACKMFMA(a1, m1, 4, B1h, B1l)
                PACKMFMA(a2, m2, 8, B2h, B2l)
            } else if (wv == 1) {
                ALOAD(a0, m0, 1) ALOAD(a1, m1, 5)
                PACKMFMA(a0, m0, 1, B0h, B0l)
                PACKMFMA(a1, m1, 5, B1h, B1l)
            } else if (wv == 2) {
                ALOAD(a0, m0, 2) ALOAD(a1, m1, 6)
                PACKMFMA(a0, m0, 2, B0h, B0l)
                PACKMFMA(a1, m1, 6, B1h, B1l)
            } else {
                ALOAD(a0, m0, 3) ALOAD(a1, m1, 7)
                PACKMFMA(a0, m0, 3, B0h, B0l)
                PACKMFMA(a1, m1, 7, B1h, B1l)
            }
        }
        __syncthreads();                    // u complete

        // ---- phase 2: load u rows, free LDS, route in registers ----
        v2f U00, U01, U02, U03;
        v2f U10, U11, U12, U13;
        v2f U20, U21, U22, U23;
        v2f U30, U31, U32, U33;
        v2f U40, U41, U42, U43;
        U40 = U41 = U42 = U43 = (v2f){0.0f, 0.0f};
        LROW(0) LROW(1) LROW(2) LROW(3)
        if (has5) LROW(4)
        __syncthreads();                    // u free for next quad

        v2f V0, V1, V2, V3;
        MEANJ(0) MEANJ(1) MEANJ(2) MEANJ(3)

        #pragma unroll 1
        for (int it = 0; it < 3; ++it) {
            v2f ssv = V0 * V0;
            ssv = pkfma(V1, V1, ssv); ssv = pkfma(V2, V2, ssv);
            ssv = pkfma(V3, V3, ssv);
            float ss = swz16_add(ssv.x + ssv.y);
            float inv = frcp(fmaxf(sqrtf(ss), 1e-12f));

            float E0 = __expf(DOTR(0) * inv);
            float E1 = __expf(DOTR(1) * inv);
            float E2 = __expf(DOTR(2) * inv);
            float E3 = __expf(DOTR(3) * inv);
            float E4 = has5 ? __expf(DOTR(4) * inv) : 0.0f;
            float ssum = dpp_add16(((E0 + E1) + (E2 + E3)) + E4);
            float rs = frcp(ssum);

            v2f e0v = {E0, E0}, e1v = {E1, E1}, e2v = {E2, E2};
            v2f e3v = {E3, E3}, e4v = {E4, E4};
            UPDJ(0) UPDJ(1) UPDJ(2) UPDJ(3)
        }

        v2f ssv = V0 * V0;
        ssv = pkfma(V1, V1, ssv); ssv = pkfma(V2, V2, ssv);
        ssv = pkfma(V3, V3, ssv);
        float ss = swz16_add(ssv.x + ssv.y);
        float scale = sqrtf(ss) * frcp(1.0f + ss);

        v2f aa0 = (sc & 4) ? V2 : V0;
        v2f aa1 = (sc & 4) ? V3 : V1;
        v2f bb0 = (sc & 2) ? aa1 : aa0;
        float res = ((sc & 1) ? bb0.y : bb0.x) * scale;
        if (sc < 8) {
            int tg = tt * 32 + o2 * 16 + jh * 8 + sc;   // global channel
            out[((bb * 256 + tg) * 32 + h) * 32 + w0 + p] = res;
        }
    }
}

extern "C" void kernel_launch(void* const* d_in, const int* in_sizes, int n_in,
                              void* d_out, int out_size, void* d_ws, size_t ws_size,
                              hipStream_t stream) {
    const float* x = (const float*)d_in[0];   // [2,128,32,32]
    const float* W = (const float*)d_in[1];   // [16,16,16,3,3]
    float* out = (float*)d_out;               // [2,256,32,32]
    (void)d_ws; (void)ws_size; (void)in_sizes; (void)n_in; (void)out_size;
    capsule_v11<<<1024, 256, 0, stream>>>(x, W, out);
}

// Round 5
// 84.508 us; speedup vs baseline: 1.0816x; 1.0816x over previous
//
#include <hip/hip_runtime.h>

// CapsuleConv2d, MI355X gfx950. ALL I/O FP32.
// B=2, C_in=128 (G=8 x M=16), 32x32, 3x3 pad 1, O=16, L=16 -> C_out=256.
// k-means (dot) routing 3 iters + squash.
//
// v12: back to v9's two-dispatch pre-pack structure (fused v10/v11 were
// kernel-level regressions: re-packed W per block, scattered A loads).
//  - prep2: packs BOTH Wbf (v9 layout) and xP (A-frag-ready bf16 hi/lo,
//    16B-vector loadable) -> hot kernel has ZERO pack VALU.
//  - capsule_v12: 8192 blocks, block = 2 pixels x 32 t (LDS 19.6 KB ->
//    8 blocks/CU = 32 waves, vs 4 blocks/50% before). MFMA uses 16 of 32
//    A rows (rows 16-31 dup, acc regs 8-15 unwritten); waves 2-3 exit
//    after the barrier; phase-2 routing is v9-VERBATIM (wave = pixel).
//  - Numerics identical to v9/v10/v11 (absmax must stay 4.882812e-4).

typedef float v2f __attribute__((ext_vector_type(2)));
typedef int   i4  __attribute__((ext_vector_type(4)));
typedef short bh8 __attribute__((ext_vector_type(8)));
typedef float f16v __attribute__((ext_vector_type(16)));

#define STR 34                          // u LDS row stride (floats)
#define XP_I4 65536                     // xP: 65536 i4 = 1 MB
#define WBF_ELEMS 73728                 // Wbf u16 count (144 KB)

#define DPP_ADD(a, ctrl)                                                     \
  a += __int_as_float(__builtin_amdgcn_update_dpp(                           \
          0, __float_as_int(a), ctrl, 0xF, 0xF, true))

__device__ __forceinline__ float dpp_add16(float x) {
    float s = x;
    DPP_ADD(s, 0x128); DPP_ADD(s, 0x124); DPP_ADD(s, 0x122); DPP_ADD(s, 0x121);
    return s;
}

__device__ __forceinline__ float swz16_add(float x) {
    int y = __builtin_amdgcn_ds_swizzle(__float_as_int(x), 0x401F);
    return x + __int_as_float(y);
}

__device__ __forceinline__ float frcp(float x) {
    return __builtin_amdgcn_rcpf(x);
}

__device__ __forceinline__ v2f pkfma(v2f a, v2f b, v2f c) {
    return __builtin_elementwise_fma(a, b, c);
}

// ---- prep2: blk<64 -> xP pack; blk>=64 -> Wbf pack (v9 layout) ----
// xP i4-index = (((b*32+h)*32+w)*8+gl)*2+half)*2+s ; 8 u16 each:
//   u16[j] = s==0 ? trunc-bf16(x[b][gl*16+half*8+j][h][w])
//          : trunc-bf16(x - hi_as_f32)
// Wbf flat idx = (((ij*8+tt)*2+s)*64 + L)*8 + j  (v9 verbatim)
__global__ __launch_bounds__(256)
void prep2_kernel(const float* __restrict__ x, const float* __restrict__ W,
                  i4* __restrict__ xP, unsigned short* __restrict__ Wbf) {
    const int blk = blockIdx.x;
    const int tid = threadIdx.x;
    if (blk < 64) {
        __shared__ float xs[128 * 33];
        const int b = blk >> 5, h = blk & 31;
        const float* xb = x + b * (128 * 32 * 32) + h * 32;
        #pragma unroll
        for (int k = 0; k < 16; ++k) {
            int idx = k * 256 + tid;
            int c = idx >> 5, w = idx & 31;
            xs[c * 33 + w] = xb[c * 1024 + w];
        }
        __syncthreads();
        i4* xo = xP + (b * 32 + h) * 1024;
        #pragma unroll
        for (int it = 0; it < 4; ++it) {
            int slot = it * 256 + tid;          // = w*32 + gl*4 + hf*2 + s
            int s  = slot & 1;
            int hf = (slot >> 1) & 1;
            int gl = (slot >> 2) & 7;
            int w  = slot >> 5;
            int c0 = gl * 16 + hf * 8;
            float f0 = xs[(c0 + 0) * 33 + w], f1 = xs[(c0 + 1) * 33 + w];
            float f2 = xs[(c0 + 2) * 33 + w], f3 = xs[(c0 + 3) * 33 + w];
            float f4 = xs[(c0 + 4) * 33 + w], f5 = xs[(c0 + 5) * 33 + w];
            float f6 = xs[(c0 + 6) * 33 + w], f7 = xs[(c0 + 7) * 33 + w];
            unsigned b0 = __float_as_uint(f0), b1 = __float_as_uint(f1);
            unsigned b2 = __float_as_uint(f2), b3 = __float_as_uint(f3);
            unsigned b4 = __float_as_uint(f4), b5 = __float_as_uint(f5);
            unsigned b6 = __float_as_uint(f6), b7 = __float_as_uint(f7);
            i4 pk;
            if (s == 0) {
                pk.x = (int)((b0 >> 16) | (b1 & 0xFFFF0000u));
                pk.y = (int)((b2 >> 16) | (b3 & 0xFFFF0000u));
                pk.z = (int)((b4 >> 16) | (b5 & 0xFFFF0000u));
                pk.w = (int)((b6 >> 16) | (b7 & 0xFFFF0000u));
            } else {
                unsigned l0 = __float_as_uint(f0 - __uint_as_float(b0 & 0xFFFF0000u));
                unsigned l1 = __float_as_uint(f1 - __uint_as_float(b1 & 0xFFFF0000u));
                unsigned l2 = __float_as_uint(f2 - __uint_as_float(b2 & 0xFFFF0000u));
                unsigned l3 = __float_as_uint(f3 - __uint_as_float(b3 & 0xFFFF0000u));
                unsigned l4 = __float_as_uint(f4 - __uint_as_float(b4 & 0xFFFF0000u));
                unsigned l5 = __float_as_uint(f5 - __uint_as_float(b5 & 0xFFFF0000u));
                unsigned l6 = __float_as_uint(f6 - __uint_as_float(b6 & 0xFFFF0000u));
                unsigned l7 = __float_as_uint(f7 - __uint_as_float(b7 & 0xFFFF0000u));
                pk.x = (int)((l0 >> 16) | (l1 & 0xFFFF0000u));
                pk.y = (int)((l2 >> 16) | (l3 & 0xFFFF0000u));
                pk.z = (int)((l4 >> 16) | (l5 & 0xFFFF0000u));
                pk.w = (int)((l6 >> 16) | (l7 & 0xFFFF0000u));
            }
            xo[slot] = pk;
        }
    } else {
        int idx = (blk - 64) * 256 + tid;     // 0..73727
        int j  = idx & 7;
        int L  = (idx >> 3) & 63;
        int s  = (idx >> 9) & 1;
        int tt = (idx >> 10) & 7;
        int ij = idx >> 13;
        int k  = (L >> 5) * 8 + j;
        int t  = tt * 32 + (L & 31);
        float wv = W[(t * 16 + k) * 9 + ij];
        unsigned bits = __float_as_uint(wv);
        unsigned hib  = bits & 0xFFFF0000u;
        unsigned short val;
        if (s == 0) val = (unsigned short)(hib >> 16);
        else {
            float lo = wv - __uint_as_float(hib);
            val = (unsigned short)(__float_as_uint(lo) >> 16);
        }
        Wbf[idx] = val;
    }
}

// ---- phase-1 macros ----
#define ALOADIJ(AH, AL, OK, IJ) {                                            \
    const int di = (IJ) / 3, dj = (IJ) % 3;                                  \
    const int hh = h + di - 1;                                               \
    const bool hok = (unsigned)hh < 32u;                                     \
    const int hhc = hok ? hh : 0;                                            \
    const int ww = w0 + pl + dj - 1;                                         \
    OK = hok && ((unsigned)ww < 32u);                                        \
    const int wwc = OK ? ww : 0;                                             \
    const int slot = (((bb * 32 + hhc) * 32 + wwc) * 8 + gl) * 2 + half;     \
    AH = xpi4[slot * 2]; AL = xpi4[slot * 2 + 1]; }

#define BLOADIJ(BH, BL, IJ) {                                                \
    BH = bfr[((IJ) * 8 + tt) * 128 + lane];                                  \
    BL = bfr[((IJ) * 8 + tt) * 128 + 64 + lane]; }

// C row r = (reg&3)+8*(reg>>2)+4*half; only regs 0-7 valid (p = reg>>2 < 2)
#define CWR(REG, IJ)                                                         \
    uLds[wroff + STR * ((((REG) >> 2) * 72) + (((REG) & 3) * 9) + (IJ))] =   \
        acc[(REG)];

#define PROCIJ(AH, AL, OK, BH, BL, IJ) {                                     \
    const i4 z_ = {0, 0, 0, 0};                                              \
    i4 ah_ = OK ? AH : z_;                                                   \
    i4 al_ = OK ? AL : z_;                                                   \
    bh8 aHi = __builtin_bit_cast(bh8, ah_);                                  \
    bh8 aLo = __builtin_bit_cast(bh8, al_);                                  \
    bh8 bHi = __builtin_bit_cast(bh8, BH);                                   \
    bh8 bLo = __builtin_bit_cast(bh8, BL);                                   \
    f16v acc = {0.f,0.f,0.f,0.f,0.f,0.f,0.f,0.f,                             \
                0.f,0.f,0.f,0.f,0.f,0.f,0.f,0.f};                            \
    acc = __builtin_amdgcn_mfma_f32_32x32x16_bf16(aHi, bLo, acc, 0, 0, 0);   \
    acc = __builtin_amdgcn_mfma_f32_32x32x16_bf16(aLo, bHi, acc, 0, 0, 0);   \
    acc = __builtin_amdgcn_mfma_f32_32x32x16_bf16(aHi, bHi, acc, 0, 0, 0);   \
    CWR(0, IJ) CWR(1, IJ) CWR(2, IJ) CWR(3, IJ)                              \
    CWR(4, IJ) CWR(5, IJ) CWR(6, IJ) CWR(7, IJ) }

// ---- phase-2 macros (v9 verbatim) ----
#define LROW(K)                                                              \
  { const v2f* r2_ = (const v2f*)(rb + (K) * 16 * STR);                      \
    U##K##0 = r2_[0]; U##K##1 = r2_[1]; U##K##2 = r2_[2]; U##K##3 = r2_[3]; }

#define DOTR(K)                                                              \
  ({ v2f d_ = U##K##0 * V0;                                                  \
     d_ = pkfma(U##K##1, V1, d_); d_ = pkfma(U##K##2, V2, d_);               \
     d_ = pkfma(U##K##3, V3, d_); swz16_add(d_.x + d_.y); })

#define MEANJ(J)                                                             \
  { v2f s_ = (U0##J + U1##J) + (U2##J + U3##J) + U4##J;                      \
    V##J.x = dpp_add16(s_.x) * (1.0f / 72.0f);                               \
    V##J.y = dpp_add16(s_.y) * (1.0f / 72.0f); }

#define UPDJ(J)                                                              \
  { v2f pv_ = e0v * U0##J;                                                   \
    pv_ = pkfma(e1v, U1##J, pv_); pv_ = pkfma(e2v, U2##J, pv_);              \
    pv_ = pkfma(e3v, U3##J, pv_); pv_ = pkfma(e4v, U4##J, pv_);              \
    V##J.x = dpp_add16(pv_.x) * rs;                                          \
    V##J.y = dpp_add16(pv_.y) * rs; }

// ---- main kernel v12: 8192 blocks, 2 pixels x 32 t, 8 blocks/CU ----
__global__ __launch_bounds__(256, 8)
void capsule_v12(const i4* __restrict__ xpi4, const i4* __restrict__ bfr,
                 float* __restrict__ out) {
    __shared__ float uLds[2 * 72 * STR];     // 19.1 KB -> 8 blocks/CU
    const int blk = blockIdx.x;              // 8192 = tt(8) x bb(2) x h(32) x wp(16)
    const int tt  = blk & 7;
    const int r   = blk >> 3;
    const int bb  = r >> 9;
    const int h   = (r >> 4) & 31;
    const int w0  = (r & 15) << 1;           // pixel pair {w0, w0+1}
    const int tid = threadIdx.x;

    // ---- phase 1: pure-load A/B frags, MFMA, CWR (regs 0-7) ----
    {
        const int lane = tid & 63;
        const int wv   = tid >> 6;
        const int pl   = (lane >> 3) & 1;    // pixel (rows 16-31 dup rows 0-15)
        const int gl   = lane & 7;           // group
        const int half = lane >> 5;          // k-half
        const int tl   = lane & 31;          // C col
        const int wroff = tl + STR * 9 * 4 * half;

        if (wv == 0) {
            i4 a0h, a0l, a1h, a1l, a2h, a2l;
            i4 b0h, b0l, b1h, b1l, b2h, b2l;
            bool ok0, ok1, ok2;
            ALOADIJ(a0h, a0l, ok0, 0) BLOADIJ(b0h, b0l, 0)
            ALOADIJ(a1h, a1l, ok1, 4) BLOADIJ(b1h, b1l, 4)
            PROCIJ(a0h, a0l, ok0, b0h, b0l, 0)
            ALOADIJ(a2h, a2l, ok2, 8) BLOADIJ(b2h, b2l, 8)
            PROCIJ(a1h, a1l, ok1, b1h, b1l, 4)
            PROCIJ(a2h, a2l, ok2, b2h, b2l, 8)
        } else if (wv == 1) {
            i4 a0h, a0l, a1h, a1l, b0h, b0l, b1h, b1l;
            bool ok0, ok1;
            ALOADIJ(a0h, a0l, ok0, 1) BLOADIJ(b0h, b0l, 1)
            ALOADIJ(a1h, a1l, ok1, 5) BLOADIJ(b1h, b1l, 5)
            PROCIJ(a0h, a0l, ok0, b0h, b0l, 1)
            PROCIJ(a1h, a1l, ok1, b1h, b1l, 5)
        } else if (wv == 2) {
            i4 a0h, a0l, a1h, a1l, b0h, b0l, b1h, b1l;
            bool ok0, ok1;
            ALOADIJ(a0h, a0l, ok0, 2) BLOADIJ(b0h, b0l, 2)
            ALOADIJ(a1h, a1l, ok1, 6) BLOADIJ(b1h, b1l, 6)
            PROCIJ(a0h, a0l, ok0, b0h, b0l, 2)
            PROCIJ(a1h, a1l, ok1, b1h, b1l, 6)
        } else {
            i4 a0h, a0l, a1h, a1l, b0h, b0l, b1h, b1l;
            bool ok0, ok1;
            ALOADIJ(a0h, a0l, ok0, 3) BLOADIJ(b0h, b0l, 3)
            ALOADIJ(a1h, a1l, ok1, 7) BLOADIJ(b1h, b1l, 7)
            PROCIJ(a0h, a0l, ok0, b0h, b0l, 3)
            PROCIJ(a1h, a1l, ok1, b1h, b1l, 7)
        }
    }
    __syncthreads();
    if (tid >= 128) return;                  // waves 2-3 done (no more barriers)

    // ---- phase 2: routing, v9 verbatim; wave = pixel (p = tid>>6) ----
    const int p  = tid >> 6;
    const int i6 = tid & 63;
    const int o2 = i6 >> 5;
    const int jh = (i6 >> 4) & 1;
    const int sc = i6 & 15;
    const bool has5 = (sc < 8);
    const float* rb = uLds + (p * 72 + sc) * STR + o2 * 16 + jh * 8;

    v2f U00, U01, U02, U03;
    v2f U10, U11, U12, U13;
    v2f U20, U21, U22, U23;
    v2f U30, U31, U32, U33;
    v2f U40, U41, U42, U43;
    U40 = U41 = U42 = U43 = (v2f){0.0f, 0.0f};
    LROW(0) LROW(1) LROW(2) LROW(3)
    if (has5) LROW(4)

    v2f V0, V1, V2, V3;
    MEANJ(0) MEANJ(1) MEANJ(2) MEANJ(3)

    #pragma unroll 1
    for (int it = 0; it < 3; ++it) {
        v2f ssv = V0 * V0;
        ssv = pkfma(V1, V1, ssv); ssv = pkfma(V2, V2, ssv);
        ssv = pkfma(V3, V3, ssv);
        float ss = swz16_add(ssv.x + ssv.y);
        float inv = frcp(fmaxf(sqrtf(ss), 1e-12f));

        float E0 = __expf(DOTR(0) * inv);
        float E1 = __expf(DOTR(1) * inv);
        float E2 = __expf(DOTR(2) * inv);
        float E3 = __expf(DOTR(3) * inv);
        float E4 = has5 ? __expf(DOTR(4) * inv) : 0.0f;
        float ssum = dpp_add16(((E0 + E1) + (E2 + E3)) + E4);
        float rs = frcp(ssum);

        v2f e0v = {E0, E0}, e1v = {E1, E1}, e2v = {E2, E2};
        v2f e3v = {E3, E3}, e4v = {E4, E4};
        UPDJ(0) UPDJ(1) UPDJ(2) UPDJ(3)
    }

    v2f ssv = V0 * V0;
    ssv = pkfma(V1, V1, ssv); ssv = pkfma(V2, V2, ssv);
    ssv = pkfma(V3, V3, ssv);
    float ss = swz16_add(ssv.x + ssv.y);
    float scale = sqrtf(ss) * frcp(1.0f + ss);

    v2f aa0 = (sc & 4) ? V2 : V0;
    v2f aa1 = (sc & 4) ? V3 : V1;
    v2f bb0 = (sc & 2) ? aa1 : aa0;
    float res = ((sc & 1) ? bb0.y : bb0.x) * scale;
    if (sc < 8) {
        int tg = tt * 32 + o2 * 16 + jh * 8 + sc;   // global channel
        out[((bb * 256 + tg) * 32 + h) * 32 + w0 + p] = res;
    }
}

// ---- fallback (tiny ws): self-contained (v9 verbatim) ----
__global__ __launch_bounds__(256, 1)
void capsule_fb(const float* __restrict__ x, const float* __restrict__ Wraw,
                float* __restrict__ out) {
    __shared__ float patch[9 * 128];
    const int blk = blockIdx.x;
    const int b = blk >> 10, h = (blk >> 5) & 31, w = blk & 31;
    const int t = threadIdx.x;

    const float* xb = x + b * (128 * 32 * 32);
    for (int idx = t; idx < 1152; idx += 256) {
        int c = idx / 9, ij = idx - c * 9;
        int di = ij / 3, dj = ij - di * 3;
        int hh = h + di - 1, ww = w + dj - 1;
        float v = 0.0f;
        if ((unsigned)hh < 32u && (unsigned)ww < 32u)
            v = xb[(c * 32 + hh) * 32 + ww];
        patch[ij * 128 + c] = v;
    }
    __syncthreads();

    float u[72];
    #pragma unroll
    for (int ij = 0; ij < 9; ++ij) {
        float wr[16];
        #pragma unroll
        for (int m = 0; m < 16; ++m) wr[m] = Wraw[(t * 16 + m) * 9 + ij];
        #pragma unroll
        for (int g = 0; g < 8; ++g) {
            float acc = 0.0f;
            #pragma unroll
            for (int m = 0; m < 16; ++m)
                acc = fmaf(patch[ij * 128 + g * 16 + m], wr[m], acc);
            u[g * 9 + ij] = acc;
        }
    }

    float v = 0.0f;
    #pragma unroll
    for (int n = 0; n < 72; ++n) v += u[n];
    v *= (1.0f / 72.0f);
    #pragma unroll 1
    for (int it = 0; it < 3; ++it) {
        float sg = dpp_add16(v * v);
        float vn = v * frcp(fmaxf(sqrtf(sg), 1e-12f));
        float ssum = 0.0f, vacc = 0.0f;
        #pragma unroll
        for (int n = 0; n < 72; ++n) {
            float pp = dpp_add16(u[n] * vn);
            float e = __expf(pp);
            ssum += e;
            vacc = fmaf(e, u[n], vacc);
        }
        v = vacc * frcp(ssum);
    }
    float sg = dpp_add16(v * v);
    float res = v * sqrtf(sg) * frcp(1.0f + sg);
    out[((b * 256 + t) * 32 + h) * 32 + w] = res;
}

extern "C" void kernel_launch(void* const* d_in, const int* in_sizes, int n_in,
                              void* d_out, int out_size, void* d_ws, size_t ws_size,
                              hipStream_t stream) {
    const float* x = (const float*)d_in[0];   // [2,128,32,32]
    const float* W = (const float*)d_in[1];   // [16,16,16,3,3]
    float* out = (float*)d_out;               // [2,256,32,32]
    i4* xP = (i4*)d_ws;                       // 1 MB
    unsigned short* Wbf = (unsigned short*)((char*)d_ws + 1048576);  // 144 KB

    const size_t need = 1048576 + (size_t)WBF_ELEMS * 2;
    if (ws_size >= need) {
        prep2_kernel<<<352, 256, 0, stream>>>(x, W, xP, Wbf);
        capsule_v12<<<8192, 256, 0, stream>>>(xP, (const i4*)Wbf, out);
    } else {
        capsule_fb<<<2048, 256, 0, stream>>>(x, W, out);
    }
}

// Round 6
// 79.599 us; speedup vs baseline: 1.1484x; 1.0617x over previous
//
#include <hip/hip_runtime.h>

// CapsuleConv2d, MI355X gfx950. ALL I/O FP32.
// B=2, C_in=128 (G=8 x M=16), 32x32, 3x3 pad 1, O=16, L=16 -> C_out=256.
// k-means (dot) routing 3 iters + squash.
//
// v13 = v9 geometry + v12 pure-load phase 1.
//  - v12's launch_bounds(256,8) capped VGPR at 64 -> spill/serialization;
//    controllable time ~44us (no better than v9). v13 returns to 4096 blocks,
//    4-pixel x 32-t, LDS 38.25KB, launch_bounds(256,4) (128 VGPR budget;
//    LDS caps residency at 4 blocks/CU regardless).
//  - prep2 (v12 verbatim): xP = A-frag-ready bf16 hi/lo (16B i4 loads),
//    Wbf = v9-layout B-frags. Hot kernel phase 1 = pure loads + MFMA + CWR.
//  - phase 2 routing v9-verbatim (wave = pixel). absmax must stay 4.882812e-4.

typedef float v2f __attribute__((ext_vector_type(2)));
typedef int   i4  __attribute__((ext_vector_type(4)));
typedef short bh8 __attribute__((ext_vector_type(8)));
typedef float f16v __attribute__((ext_vector_type(16)));

#define STR 34                          // u LDS row stride (floats)
#define WBF_ELEMS 73728                 // Wbf u16 count (144 KB)

#define DPP_ADD(a, ctrl)                                                     \
  a += __int_as_float(__builtin_amdgcn_update_dpp(                           \
          0, __float_as_int(a), ctrl, 0xF, 0xF, true))

__device__ __forceinline__ float dpp_add16(float x) {
    float s = x;
    DPP_ADD(s, 0x128); DPP_ADD(s, 0x124); DPP_ADD(s, 0x122); DPP_ADD(s, 0x121);
    return s;
}

__device__ __forceinline__ float swz16_add(float x) {
    int y = __builtin_amdgcn_ds_swizzle(__float_as_int(x), 0x401F);
    return x + __int_as_float(y);
}

__device__ __forceinline__ float frcp(float x) {
    return __builtin_amdgcn_rcpf(x);
}

__device__ __forceinline__ v2f pkfma(v2f a, v2f b, v2f c) {
    return __builtin_elementwise_fma(a, b, c);
}

// ---- prep2 (v12 verbatim): blk<64 -> xP pack; blk>=64 -> Wbf pack ----
// xP i4-index = ((((b*32+h)*32+w)*8+gl)*2+half)*2+s ; 8 bf16 u16 each.
// Wbf flat idx = (((ij*8+tt)*2+s)*64 + L)*8 + j  (v9 verbatim)
__global__ __launch_bounds__(256)
void prep2_kernel(const float* __restrict__ x, const float* __restrict__ W,
                  i4* __restrict__ xP, unsigned short* __restrict__ Wbf) {
    const int blk = blockIdx.x;
    const int tid = threadIdx.x;
    if (blk < 64) {
        __shared__ float xs[128 * 33];
        const int b = blk >> 5, h = blk & 31;
        const float* xb = x + b * (128 * 32 * 32) + h * 32;
        #pragma unroll
        for (int k = 0; k < 16; ++k) {
            int idx = k * 256 + tid;
            int c = idx >> 5, w = idx & 31;
            xs[c * 33 + w] = xb[c * 1024 + w];
        }
        __syncthreads();
        i4* xo = xP + (b * 32 + h) * 1024;
        #pragma unroll
        for (int it = 0; it < 4; ++it) {
            int slot = it * 256 + tid;          // = w*32 + gl*4 + hf*2 + s
            int s  = slot & 1;
            int hf = (slot >> 1) & 1;
            int gl = (slot >> 2) & 7;
            int w  = slot >> 5;
            int c0 = gl * 16 + hf * 8;
            float f0 = xs[(c0 + 0) * 33 + w], f1 = xs[(c0 + 1) * 33 + w];
            float f2 = xs[(c0 + 2) * 33 + w], f3 = xs[(c0 + 3) * 33 + w];
            float f4 = xs[(c0 + 4) * 33 + w], f5 = xs[(c0 + 5) * 33 + w];
            float f6 = xs[(c0 + 6) * 33 + w], f7 = xs[(c0 + 7) * 33 + w];
            unsigned b0 = __float_as_uint(f0), b1 = __float_as_uint(f1);
            unsigned b2 = __float_as_uint(f2), b3 = __float_as_uint(f3);
            unsigned b4 = __float_as_uint(f4), b5 = __float_as_uint(f5);
            unsigned b6 = __float_as_uint(f6), b7 = __float_as_uint(f7);
            i4 pk;
            if (s == 0) {
                pk.x = (int)((b0 >> 16) | (b1 & 0xFFFF0000u));
                pk.y = (int)((b2 >> 16) | (b3 & 0xFFFF0000u));
                pk.z = (int)((b4 >> 16) | (b5 & 0xFFFF0000u));
                pk.w = (int)((b6 >> 16) | (b7 & 0xFFFF0000u));
            } else {
                unsigned l0 = __float_as_uint(f0 - __uint_as_float(b0 & 0xFFFF0000u));
                unsigned l1 = __float_as_uint(f1 - __uint_as_float(b1 & 0xFFFF0000u));
                unsigned l2 = __float_as_uint(f2 - __uint_as_float(b2 & 0xFFFF0000u));
                unsigned l3 = __float_as_uint(f3 - __uint_as_float(b3 & 0xFFFF0000u));
                unsigned l4 = __float_as_uint(f4 - __uint_as_float(b4 & 0xFFFF0000u));
                unsigned l5 = __float_as_uint(f5 - __uint_as_float(b5 & 0xFFFF0000u));
                unsigned l6 = __float_as_uint(f6 - __uint_as_float(b6 & 0xFFFF0000u));
                unsigned l7 = __float_as_uint(f7 - __uint_as_float(b7 & 0xFFFF0000u));
                pk.x = (int)((l0 >> 16) | (l1 & 0xFFFF0000u));
                pk.y = (int)((l2 >> 16) | (l3 & 0xFFFF0000u));
                pk.z = (int)((l4 >> 16) | (l5 & 0xFFFF0000u));
                pk.w = (int)((l6 >> 16) | (l7 & 0xFFFF0000u));
            }
            xo[slot] = pk;
        }
    } else {
        int idx = (blk - 64) * 256 + tid;     // 0..73727
        int j  = idx & 7;
        int L  = (idx >> 3) & 63;
        int s  = (idx >> 9) & 1;
        int tt = (idx >> 10) & 7;
        int ij = idx >> 13;
        int k  = (L >> 5) * 8 + j;
        int t  = tt * 32 + (L & 31);
        float wv = W[(t * 16 + k) * 9 + ij];
        unsigned bits = __float_as_uint(wv);
        unsigned hib  = bits & 0xFFFF0000u;
        unsigned short val;
        if (s == 0) val = (unsigned short)(hib >> 16);
        else {
            float lo = wv - __uint_as_float(hib);
            val = (unsigned short)(__float_as_uint(lo) >> 16);
        }
        Wbf[idx] = val;
    }
}

// ---- phase-1 macros (pure loads; pl in 0..3, 4-pixel quad) ----
#define ALOADIJ(AH, AL, OK, IJ) {                                            \
    const int di = (IJ) / 3, dj = (IJ) % 3;                                  \
    const int hh = h + di - 1;                                               \
    const bool hok = (unsigned)hh < 32u;                                     \
    const int hhc = hok ? hh : 0;                                            \
    const int ww = w0 + pl + dj - 1;                                         \
    OK = hok && ((unsigned)ww < 32u);                                        \
    const int wwc = OK ? ww : 0;                                             \
    const int slot = (((bb * 32 + hhc) * 32 + wwc) * 8 + gl) * 2 + half;     \
    AH = xpi4[slot * 2]; AL = xpi4[slot * 2 + 1]; }

#define BLOADIJ(BH, BL, IJ) {                                                \
    BH = bfr[((IJ) * 8 + tt) * 128 + lane];                                  \
    BL = bfr[((IJ) * 8 + tt) * 128 + 64 + lane]; }

// C row r = (reg&3)+8*(reg>>2)+4*half: p=reg>>2, g=(reg&3)+4*half
#define CWR(REG, IJ)                                                         \
    uLds[wroff + STR * ((((REG) >> 2) * 72) + (((REG) & 3) * 9) + (IJ))] =   \
        acc[(REG)];

#define PROCIJ(AH, AL, OK, BH, BL, IJ) {                                     \
    const i4 z_ = {0, 0, 0, 0};                                              \
    i4 ah_ = OK ? AH : z_;                                                   \
    i4 al_ = OK ? AL : z_;                                                   \
    bh8 aHi = __builtin_bit_cast(bh8, ah_);                                  \
    bh8 aLo = __builtin_bit_cast(bh8, al_);                                  \
    bh8 bHi = __builtin_bit_cast(bh8, BH);                                   \
    bh8 bLo = __builtin_bit_cast(bh8, BL);                                   \
    f16v acc = {0.f,0.f,0.f,0.f,0.f,0.f,0.f,0.f,                             \
                0.f,0.f,0.f,0.f,0.f,0.f,0.f,0.f};                            \
    acc = __builtin_amdgcn_mfma_f32_32x32x16_bf16(aHi, bLo, acc, 0, 0, 0);   \
    acc = __builtin_amdgcn_mfma_f32_32x32x16_bf16(aLo, bHi, acc, 0, 0, 0);   \
    acc = __builtin_amdgcn_mfma_f32_32x32x16_bf16(aHi, bHi, acc, 0, 0, 0);   \
    CWR(0, IJ)  CWR(1, IJ)  CWR(2, IJ)  CWR(3, IJ)                           \
    CWR(4, IJ)  CWR(5, IJ)  CWR(6, IJ)  CWR(7, IJ)                           \
    CWR(8, IJ)  CWR(9, IJ)  CWR(10, IJ) CWR(11, IJ)                          \
    CWR(12, IJ) CWR(13, IJ) CWR(14, IJ) CWR(15, IJ) }

// ---- phase-2 macros (v9 verbatim) ----
#define LROW(K)                                                              \
  { const v2f* r2_ = (const v2f*)(rb + (K) * 16 * STR);                      \
    U##K##0 = r2_[0]; U##K##1 = r2_[1]; U##K##2 = r2_[2]; U##K##3 = r2_[3]; }

#define DOTR(K)                                                              \
  ({ v2f d_ = U##K##0 * V0;                                                  \
     d_ = pkfma(U##K##1, V1, d_); d_ = pkfma(U##K##2, V2, d_);               \
     d_ = pkfma(U##K##3, V3, d_); swz16_add(d_.x + d_.y); })

#define MEANJ(J)                                                             \
  { v2f s_ = (U0##J + U1##J) + (U2##J + U3##J) + U4##J;                      \
    V##J.x = dpp_add16(s_.x) * (1.0f / 72.0f);                               \
    V##J.y = dpp_add16(s_.y) * (1.0f / 72.0f); }

#define UPDJ(J)                                                              \
  { v2f pv_ = e0v * U0##J;                                                   \
    pv_ = pkfma(e1v, U1##J, pv_); pv_ = pkfma(e2v, U2##J, pv_);              \
    pv_ = pkfma(e3v, U3##J, pv_); pv_ = pkfma(e4v, U4##J, pv_);              \
    V##J.x = dpp_add16(pv_.x) * rs;                                          \
    V##J.y = dpp_add16(pv_.y) * rs; }

// ---- main kernel v13: 4096 blocks, 4 pixels x 32 t, pure-load phase 1 ----
__global__ __launch_bounds__(256, 4)
void capsule_v13(const i4* __restrict__ xpi4, const i4* __restrict__ bfr,
                 float* __restrict__ out) {
    __shared__ float uLds[4 * 72 * STR];     // 38.25 KB -> 4 blocks/CU
    const int blk = blockIdx.x;              // 4096 = tt(8) x bb(2) x h(32) x wq(8)
    const int tt  = blk & 7;
    const int q   = blk >> 3;
    const int bb  = q >> 8;
    const int r   = q & 255;
    const int h   = r >> 3;
    const int w0  = (r & 7) << 2;
    const int tid = threadIdx.x;

    // ---- phase 1: pure-load A/B frags, MFMA, CWR (all 16 regs) ----
    {
        const int lane = tid & 63;
        const int wv   = tid >> 6;
        const int pl   = (lane & 31) >> 3;   // pixel within quad
        const int gl   = lane & 7;           // group
        const int half = lane >> 5;          // k-half
        const int tl   = lane & 31;          // C col
        const int wroff = tl + STR * 9 * 4 * half;

        if (wv == 0) {
            i4 a0h, a0l, a1h, a1l, a2h, a2l;
            i4 b0h, b0l, b1h, b1l, b2h, b2l;
            bool ok0, ok1, ok2;
            ALOADIJ(a0h, a0l, ok0, 0) BLOADIJ(b0h, b0l, 0)
            ALOADIJ(a1h, a1l, ok1, 4) BLOADIJ(b1h, b1l, 4)
            PROCIJ(a0h, a0l, ok0, b0h, b0l, 0)
            ALOADIJ(a2h, a2l, ok2, 8) BLOADIJ(b2h, b2l, 8)
            PROCIJ(a1h, a1l, ok1, b1h, b1l, 4)
            PROCIJ(a2h, a2l, ok2, b2h, b2l, 8)
        } else if (wv == 1) {
            i4 a0h, a0l, a1h, a1l, b0h, b0l, b1h, b1l;
            bool ok0, ok1;
            ALOADIJ(a0h, a0l, ok0, 1) BLOADIJ(b0h, b0l, 1)
            ALOADIJ(a1h, a1l, ok1, 5) BLOADIJ(b1h, b1l, 5)
            PROCIJ(a0h, a0l, ok0, b0h, b0l, 1)
            PROCIJ(a1h, a1l, ok1, b1h, b1l, 5)
        } else if (wv == 2) {
            i4 a0h, a0l, a1h, a1l, b0h, b0l, b1h, b1l;
            bool ok0, ok1;
            ALOADIJ(a0h, a0l, ok0, 2) BLOADIJ(b0h, b0l, 2)
            ALOADIJ(a1h, a1l, ok1, 6) BLOADIJ(b1h, b1l, 6)
            PROCIJ(a0h, a0l, ok0, b0h, b0l, 2)
            PROCIJ(a1h, a1l, ok1, b1h, b1l, 6)
        } else {
            i4 a0h, a0l, a1h, a1l, b0h, b0l, b1h, b1l;
            bool ok0, ok1;
            ALOADIJ(a0h, a0l, ok0, 3) BLOADIJ(b0h, b0l, 3)
            ALOADIJ(a1h, a1l, ok1, 7) BLOADIJ(b1h, b1l, 7)
            PROCIJ(a0h, a0l, ok0, b0h, b0l, 3)
            PROCIJ(a1h, a1l, ok1, b1h, b1l, 7)
        }
    }
    __syncthreads();

    // ---- phase 2: routing, v9 verbatim; wave = pixel (p = tid>>6) ----
    const int p  = tid >> 6;
    const int i6 = tid & 63;
    const int o2 = i6 >> 5;
    const int jh = (i6 >> 4) & 1;
    const int sc = i6 & 15;
    const bool has5 = (sc < 8);
    const float* rb = uLds + (p * 72 + sc) * STR + o2 * 16 + jh * 8;

    v2f U00, U01, U02, U03;
    v2f U10, U11, U12, U13;
    v2f U20, U21, U22, U23;
    v2f U30, U31, U32, U33;
    v2f U40, U41, U42, U43;
    U40 = U41 = U42 = U43 = (v2f){0.0f, 0.0f};
    LROW(0) LROW(1) LROW(2) LROW(3)
    if (has5) LROW(4)

    v2f V0, V1, V2, V3;
    MEANJ(0) MEANJ(1) MEANJ(2) MEANJ(3)

    #pragma unroll 1
    for (int it = 0; it < 3; ++it) {
        v2f ssv = V0 * V0;
        ssv = pkfma(V1, V1, ssv); ssv = pkfma(V2, V2, ssv);
        ssv = pkfma(V3, V3, ssv);
        float ss = swz16_add(ssv.x + ssv.y);
        float inv = frcp(fmaxf(sqrtf(ss), 1e-12f));

        float E0 = __expf(DOTR(0) * inv);
        float E1 = __expf(DOTR(1) * inv);
        float E2 = __expf(DOTR(2) * inv);
        float E3 = __expf(DOTR(3) * inv);
        float E4 = has5 ? __expf(DOTR(4) * inv) : 0.0f;
        float ssum = dpp_add16(((E0 + E1) + (E2 + E3)) + E4);
        float rs = frcp(ssum);

        v2f e0v = {E0, E0}, e1v = {E1, E1}, e2v = {E2, E2};
        v2f e3v = {E3, E3}, e4v = {E4, E4};
        UPDJ(0) UPDJ(1) UPDJ(2) UPDJ(3)
    }

    v2f ssv = V0 * V0;
    ssv = pkfma(V1, V1, ssv); ssv = pkfma(V2, V2, ssv);
    ssv = pkfma(V3, V3, ssv);
    float ss = swz16_add(ssv.x + ssv.y);
    float scale = sqrtf(ss) * frcp(1.0f + ss);

    v2f aa0 = (sc & 4) ? V2 : V0;
    v2f aa1 = (sc & 4) ? V3 : V1;
    v2f bb0 = (sc & 2) ? aa1 : aa0;
    float res = ((sc & 1) ? bb0.y : bb0.x) * scale;
    if (sc < 8) {
        int tg = tt * 32 + o2 * 16 + jh * 8 + sc;   // global channel
        out[((bb * 256 + tg) * 32 + h) * 32 + w0 + p] = res;
    }
}

// ---- fallback (tiny ws): self-contained (v9 verbatim) ----
__global__ __launch_bounds__(256, 1)
void capsule_fb(const float* __restrict__ x, const float* __restrict__ Wraw,
                float* __restrict__ out) {
    __shared__ float patch[9 * 128];
    const int blk = blockIdx.x;
    const int b = blk >> 10, h = (blk >> 5) & 31, w = blk & 31;
    const int t = threadIdx.x;

    const float* xb = x + b * (128 * 32 * 32);
    for (int idx = t; idx < 1152; idx += 256) {
        int c = idx / 9, ij = idx - c * 9;
        int di = ij / 3, dj = ij - di * 3;
        int hh = h + di - 1, ww = w + dj - 1;
        float v = 0.0f;
        if ((unsigned)hh < 32u && (unsigned)ww < 32u)
            v = xb[(c * 32 + hh) * 32 + ww];
        patch[ij * 128 + c] = v;
    }
    __syncthreads();

    float u[72];
    #pragma unroll
    for (int ij = 0; ij < 9; ++ij) {
        float wr[16];
        #pragma unroll
        for (int m = 0; m < 16; ++m) wr[m] = Wraw[(t * 16 + m) * 9 + ij];
        #pragma unroll
        for (int g = 0; g < 8; ++g) {
            float acc = 0.0f;
            #pragma unroll
            for (int m = 0; m < 16; ++m)
                acc = fmaf(patch[ij * 128 + g * 16 + m], wr[m], acc);
            u[g * 9 + ij] = acc;
        }
    }

    float v = 0.0f;
    #pragma unroll
    for (int n = 0; n < 72; ++n) v += u[n];
    v *= (1.0f / 72.0f);
    #pragma unroll 1
    for (int it = 0; it < 3; ++it) {
        float sg = dpp_add16(v * v);
        float vn = v * frcp(fmaxf(sqrtf(sg), 1e-12f));
        float ssum = 0.0f, vacc = 0.0f;
        #pragma unroll
        for (int n = 0; n < 72; ++n) {
            float pp = dpp_add16(u[n] * vn);
            float e = __expf(pp);
            ssum += e;
            vacc = fmaf(e, u[n], vacc);
        }
        v = vacc * frcp(ssum);
    }
    float sg = dpp_add16(v * v);
    float res = v * sqrtf(sg) * frcp(1.0f + sg);
    out[((b * 256 + t) * 32 + h) * 32 + w] = res;
}

extern "C" void kernel_launch(void* const* d_in, const int* in_sizes, int n_in,
                              void* d_out, int out_size, void* d_ws, size_t ws_size,
                              hipStream_t stream) {
    const float* x = (const float*)d_in[0];   // [2,128,32,32]
    const float* W = (const float*)d_in[1];   // [16,16,16,3,3]
    float* out = (float*)d_out;               // [2,256,32,32]
    i4* xP = (i4*)d_ws;                       // 1 MB
    unsigned short* Wbf = (unsigned short*)((char*)d_ws + 1048576);  // 144 KB

    const size_t need = 1048576 + (size_t)WBF_ELEMS * 2;
    if (ws_size >= need) {
        prep2_kernel<<<352, 256, 0, stream>>>(x, W, xP, Wbf);
        capsule_v13<<<4096, 256, 0, stream>>>(xP, (const i4*)Wbf, out);
    } else {
        capsule_fb<<<2048, 256, 0, stream>>>(x, W, out);
    }
}